// Round 12
// baseline (528.042 us; speedup 1.0000x reference)
//
#include <hip/hip_runtime.h>
#include <stdint.h>

#define HD  128
#define DIN 64
#define DE  32

typedef unsigned int u32; typedef unsigned short u16; typedef unsigned char u8;
typedef long i64_;
typedef short s16x8 __attribute__((ext_vector_type(8)));
typedef float f32x4 __attribute__((ext_vector_type(4)));
typedef float f32x2 __attribute__((ext_vector_type(2)));

#define MFMA16(a,b,c)  __builtin_amdgcn_mfma_f32_16x16x32_bf16((a),(b),(c),0,0,0)
#define MFMAF8(a,b,c)  __builtin_amdgcn_mfma_f32_16x16x32_fp8_fp8((a),(b),(c),0,0,0)

__device__ __forceinline__ float lrelu(float x){ return x > 0.f ? x : 0.01f*x; }
__device__ __forceinline__ float sigmoidf_(float x){ return 1.f/(1.f + __expf(-x)); }
__device__ __forceinline__ float tanhf_(float x){
    float t = fminf(fmaxf(x, -15.f), 15.f);
    float e = __expf(2.f*t);
    return (e - 1.f)/(e + 1.f);
}
__device__ __forceinline__ float eluf_(float x){ return x > 0.f ? x : expm1f(x); }

__device__ __forceinline__ u16 f32_to_bf16(float x){
    u32 u = __float_as_uint(x);
    u += 0x7FFFu + ((u >> 16) & 1u);
    return (u16)(u >> 16);
}
__device__ __forceinline__ float bf16lo(u32 u){ return __uint_as_float((u & 0xFFFFu) << 16); }
__device__ __forceinline__ float bf16hi(u32 u){ return __uint_as_float(u & 0xFFFF0000u); }
__device__ __forceinline__ float bf16f(u16 h){ return __uint_as_float(((u32)h) << 16); }
__device__ __forceinline__ u32 pk2(float a, float b){
    return (u32)f32_to_bf16(a) | ((u32)f32_to_bf16(b) << 16);
}
// HW OCP e4m3fn converters (gfx950)
__device__ __forceinline__ u8 hw_f8(float v){
    return (u8)__builtin_amdgcn_cvt_pk_fp8_f32(v, v, 0, false);
}
__device__ __forceinline__ u32 hw_f8x4(float a, float b, float c, float d){
    u32 r = (u32)__builtin_amdgcn_cvt_pk_fp8_f32(a, b, 0, false);
    r = (u32)__builtin_amdgcn_cvt_pk_fp8_f32(c, d, (int)r, true);
    return r;
}
__device__ __forceinline__ f32x2 hw_f8_dec2(u32 u){   // decodes bytes [0:1]
    return __builtin_amdgcn_cvt_pk_f32_fp8((int)u, false);
}
__device__ __forceinline__ f32x2 hw_f8_dec2_hi(u32 u){ // decodes bytes [2:3]
    return __builtin_amdgcn_cvt_pk_f32_fp8((int)u, true);
}

__device__ __forceinline__ float wave_max(float v){
    #pragma unroll
    for (int o = 32; o > 0; o >>= 1) v = fmaxf(v, __shfl_xor(v, o, 64));
    return v;
}
__device__ __forceinline__ float wave_sum(float v){
    #pragma unroll
    for (int o = 32; o > 0; o >>= 1) v += __shfl_xor(v, o, 64);
    return v;
}

// ---------------- weight prep: fp32 -> bf16 (+ fp8 GRU B-pack) ----------------
__global__ void k_prep(const float* __restrict__ W1, const float* __restrict__ W2,
                       const float* __restrict__ Went,
                       const float* __restrict__ Wih, const float* __restrict__ Whh,
                       u16* __restrict__ W1b, u16* __restrict__ W2b,
                       u16* __restrict__ Wentb, u8* __restrict__ Bgf8)
{
    int i = blockIdx.x*256 + threadIdx.x;
    if (i < 20480){ W1b[i] = f32_to_bf16(W1[i]); return; }
    i -= 20480;
    if (i < 16384){ W2b[i] = f32_to_bf16(W2[i]); return; }
    i -= 16384;
    if (i < 8192){ Wentb[i] = f32_to_bf16(Went[i]); return; }
    i -= 8192;
    if (i < 131072){
        int col = i >> 8, k = i & 255;
        int g = col >> 7, j = col & 127;
        float v;
        if      (g == 0) v = (k < 128) ? Wih[j*128 + k]        : Whh[j*128 + k - 128];
        else if (g == 1) v = (k < 128) ? Wih[(128+j)*128 + k]  : Whh[(128+j)*128 + k - 128];
        else if (g == 2) v = (k < 128) ? Wih[(256+j)*128 + k]  : 0.f;
        else             v = (k < 128) ? 0.f                   : Whh[(256+j)*128 + k - 128];
        Bgf8[i] = hw_f8(v);
    }
}

// ---------------- K1 (MFMA): xeb = bf16(lrelu(x@W^T+b)); Agru xe-half fp8; r_dst ----------------
__global__ __launch_bounds__(256, 2) void k_enter_mfma(
    const float* __restrict__ x, const u16* __restrict__ Wb, const float* __restrict__ be,
    const float* __restrict__ att_r, u16* __restrict__ xeb, u8* __restrict__ Agru,
    float* __restrict__ r_out, int N)
{
    __shared__ __align__(16) u8 sA[64*144];
    __shared__ __align__(16) u8 sO[64*272];
    int t = threadIdx.x, w = t >> 6, lane = t & 63, l15 = lane & 15, l4 = lane >> 4;
    int tile = blockIdx.x;

    s16x8 bfr[2][2];
    #pragma unroll
    for (int kf = 0; kf < 2; ++kf)
        #pragma unroll
        for (int cf = 0; cf < 2; ++cf)
            bfr[kf][cf] = *(const s16x8*)(Wb + (size_t)(w*32 + cf*16 + l15)*64 + kf*32 + l4*8);

    int el = t >> 2, q = t & 3;
    size_t n = (size_t)tile*64 + el;
    {
        const float4* xs = (const float4*)(x + n*64 + q*16);
        float4 f0 = xs[0], f1 = xs[1], f2 = xs[2], f3 = xs[3];
        uint4 o0, o1;
        o0.x = pk2(f0.x,f0.y); o0.y = pk2(f0.z,f0.w); o0.z = pk2(f1.x,f1.y); o0.w = pk2(f1.z,f1.w);
        o1.x = pk2(f2.x,f2.y); o1.y = pk2(f2.z,f2.w); o1.z = pk2(f3.x,f3.y); o1.w = pk2(f3.z,f3.w);
        *(uint4*)(sA + el*144 + q*32)      = o0;
        *(uint4*)(sA + el*144 + q*32 + 16) = o1;
    }
    __syncthreads();

    f32x4 acc[4][2];
    #pragma unroll
    for (int rf = 0; rf < 4; ++rf){ acc[rf][0] = (f32x4)0.f; acc[rf][1] = (f32x4)0.f; }
    #pragma unroll
    for (int kf = 0; kf < 2; ++kf){
        s16x8 a[4];
        #pragma unroll
        for (int rf = 0; rf < 4; ++rf)
            a[rf] = *(const s16x8*)(sA + (rf*16 + l15)*144 + kf*64 + l4*16);
        #pragma unroll
        for (int rf = 0; rf < 4; ++rf){
            acc[rf][0] = MFMA16(a[rf], bfr[kf][0], acc[rf][0]);
            acc[rf][1] = MFMA16(a[rf], bfr[kf][1], acc[rf][1]);
        }
    }
    float b0 = be[w*32 + l15], b1 = be[w*32 + 16 + l15];
    #pragma unroll
    for (int rf = 0; rf < 4; ++rf)
        #pragma unroll
        for (int r = 0; r < 4; ++r){
            int row = rf*16 + l4*4 + r;
            *(u16*)(sO + row*272 + (w*32 + l15)*2)      = f32_to_bf16(lrelu(acc[rf][0][r] + b0));
            *(u16*)(sO + row*272 + (w*32 + 16 + l15)*2) = f32_to_bf16(lrelu(acc[rf][1][r] + b1));
        }
    __syncthreads();

    float dot = 0.f;
    #pragma unroll
    for (int i = 0; i < 4; ++i){
        uint4 v = *(const uint4*)(sO + el*272 + q*64 + 16*i);
        ((uint4*)xeb)[n*16 + q*4 + i] = v;
        float f0 = bf16lo(v.x), f1 = bf16hi(v.x), f2 = bf16lo(v.y), f3 = bf16hi(v.y);
        float f4 = bf16lo(v.z), f5 = bf16hi(v.z), f6 = bf16lo(v.w), f7 = bf16hi(v.w);
        const float* al = att_r + q*32 + 8*i;
        dot = fmaf(f0, al[0], dot); dot = fmaf(f1, al[1], dot);
        dot = fmaf(f2, al[2], dot); dot = fmaf(f3, al[3], dot);
        dot = fmaf(f4, al[4], dot); dot = fmaf(f5, al[5], dot);
        dot = fmaf(f6, al[6], dot); dot = fmaf(f7, al[7], dot);
        uint2 p; p.x = hw_f8x4(f0, f1, f2, f3); p.y = hw_f8x4(f4, f5, f6, f7);
        *(uint2*)(Agru + n*256 + 128 + q*32 + i*8) = p;   // xe half (K>=128)
    }
    dot += __shfl_xor(dot, 1); dot += __shfl_xor(dot, 2);
    if (q == 0) r_out[n] = dot;
}

// ---------------- CSR build ----------------
__global__ void k_hist(const int* __restrict__ dst, int* __restrict__ deg, int E){
    int e = blockIdx.x*256 + threadIdx.x;
    if (e < E) atomicAdd(&deg[dst[e]], 1);
}
__global__ __launch_bounds__(256) void k_scan_a(
    const int* __restrict__ deg, int* __restrict__ rs, int* __restrict__ btot, int N)
{
    __shared__ int sd[256];
    int b = blockIdx.x, t = threadIdx.x;
    int base = b*1024 + t*4;
    int d0 = deg[base], d1 = deg[base+1], d2 = deg[base+2], d3 = deg[base+3];
    int s = d0 + d1 + d2 + d3;
    sd[t] = s; __syncthreads();
    for (int o = 1; o < 256; o <<= 1){
        int v = (t >= o) ? sd[t-o] : 0;
        __syncthreads();
        sd[t] += v;
        __syncthreads();
    }
    int ex = sd[t] - s;
    rs[base]   = ex;
    rs[base+1] = ex + d0;
    rs[base+2] = ex + d0 + d1;
    rs[base+3] = ex + d0 + d1 + d2;
    if (t == 0) btot[b] = sd[255];
}
__global__ __launch_bounds__(256) void k_scan_b(const int* __restrict__ btot, int* __restrict__ bbase){
    __shared__ int sd[256];
    int t = threadIdx.x;
    int s = btot[t];
    sd[t] = s; __syncthreads();
    for (int o = 1; o < 256; o <<= 1){
        int v = (t >= o) ? sd[t-o] : 0;
        __syncthreads();
        sd[t] += v;
        __syncthreads();
    }
    bbase[t] = sd[t] - s;
}
__global__ void k_scan_c(int* __restrict__ rs, const int* __restrict__ bbase, int N, int E){
    int i = blockIdx.x*256 + threadIdx.x;
    if (i < N) rs[i] += bbase[i >> 10];
    if (i == 0) rs[N] = E;
}

// ---------------- K2 (MFMA, 8-wave, 2-barrier pipeline, HW fp8, inline scatter) ----------------
__global__ __launch_bounds__(512, 4) void k_edge_mfma(
    const u16* __restrict__ xeb, const float* __restrict__ ea,
    const u16* __restrict__ W1b, const float* __restrict__ att_l,
    const float* __restrict__ r_dst, const int* __restrict__ src, const int* __restrict__ dst,
    const int* __restrict__ rs, int* __restrict__ cnt,
    u8* __restrict__ m, float* __restrict__ alpha, int ntiles, int E)
{
    __shared__ __align__(16) u8 sA[64*336];
    __shared__ __align__(16) u8 sM[64*144];
    int t = threadIdx.x, w = t >> 6, lane = t & 63, l15 = lane & 15, l4 = lane >> 4;

    s16x8 bfr[5];                 // wave w owns cols [w*16, w*16+16)
    #pragma unroll
    for (int kf = 0; kf < 5; ++kf)
        bfr[kf] = *(const s16x8*)(W1b + (size_t)(w*16 + l15)*160 + kf*32 + l4*8);

    int el = t >> 3, q = t & 7;   // 64 edges/tile, 8 threads/edge
    int stride = gridDim.x;
    int tile = blockIdx.x;

    uint4 cx0, cx1;
    u32 ce0, ce1;
    int   pe = 0;
    float rdv = 0.f;
    {
        int e = tile*64 + el;
        if (tile < ntiles && e < E){
            int sn = src[e];
            const uint4* xs = (const uint4*)xeb + (size_t)sn*16 + q*2;
            cx0 = xs[0]; cx1 = xs[1];
            float4 f = *(const float4*)(ea + (size_t)e*32 + q*4);
            ce0 = pk2(f.x, f.y); ce1 = pk2(f.z, f.w);
            if (q == 0){
                int d = dst[e];
                pe  = rs[d] + atomicAdd(&cnt[d], 1);
                rdv = r_dst[d];
            }
        }
    }

    int   ptile = -1;
    int   pe_prev = 0;
    float rdv_prev = 0.f;

    for (; tile < ntiles; tile += stride){
        int e = tile*64 + el;
        if (e < E){
            uint4* d = (uint4*)(sA + el*336 + q*32);
            d[0] = cx0; d[1] = cx1;
            *(u32*)(sA + el*336 + 256 + q*8)     = ce0;
            *(u32*)(sA + el*336 + 256 + q*8 + 4) = ce1;
        }
        int pe_cur = __shfl(pe, (lane & 7)*8 + 0, 64);   // broadcast q==0's pe within edge group
        pe_cur = pe;                                     // (pe only valid on q==0; fixed below)
        float rdv_cur = rdv;

        int nt = tile + stride;
        if (nt < ntiles){
            int e2 = nt*64 + el;
            if (e2 < E){
                int sn = src[e2];
                const uint4* xs = (const uint4*)xeb + (size_t)sn*16 + q*2;
                cx0 = xs[0]; cx1 = xs[1];
                float4 f = *(const float4*)(ea + (size_t)e2*32 + q*4);
                ce0 = pk2(f.x, f.y); ce1 = pk2(f.z, f.w);
                if (q == 0){
                    int d = dst[e2];
                    pe  = rs[d] + atomicAdd(&cnt[d], 1);
                    rdv = r_dst[d];
                }
            }
        }

        // epilogue for previous tile (reads sM written last iteration)
        if (ptile >= 0){
            int ep = ptile*64 + el;
            if (ep < E){
                int pp = __shfl(pe_prev, el*8, 64);      // edge's pe lives on its q==0 thread
                uint4 v = *(const uint4*)(sM + el*144 + q*16);
                ((uint4*)m)[(size_t)pp*8 + q] = v;
                u32 ws[4] = {v.x, v.y, v.z, v.w};
                float dotv = 0.f;
                #pragma unroll
                for (int i = 0; i < 4; ++i){
                    f32x2 fa = hw_f8_dec2(ws[i]);
                    f32x2 fb = hw_f8_dec2_hi(ws[i]);
                    const float* al = att_l + q*16 + i*4;
                    dotv = fmaf(fa.x, al[0], dotv); dotv = fmaf(fa.y, al[1], dotv);
                    dotv = fmaf(fb.x, al[2], dotv); dotv = fmaf(fb.y, al[3], dotv);
                }
                dotv += __shfl_xor(dotv, 1); dotv += __shfl_xor(dotv, 2); dotv += __shfl_xor(dotv, 4);
                if (q == 0) alpha[pp] = lrelu(dotv + __shfl(rdv_prev, el*8, 64));
            }
        }
        __syncthreads();

        f32x4 acc[4];
        #pragma unroll
        for (int rf = 0; rf < 4; ++rf) acc[rf] = (f32x4)0.f;
        #pragma unroll
        for (int kf = 0; kf < 5; ++kf){
            s16x8 a[4];
            #pragma unroll
            for (int rf = 0; rf < 4; ++rf)
                a[rf] = *(const s16x8*)(sA + (rf*16 + l15)*336 + kf*64 + l4*16);
            #pragma unroll
            for (int rf = 0; rf < 4; ++rf)
                acc[rf] = MFMA16(a[rf], bfr[kf], acc[rf]);
        }

        // conflict-free fp8 epilogue: pack 4 rows -> u32, 4x4 byte transpose across quad lanes
        {
            int colbase = w*16 + (l15 & 12);
            int rowsub  = l4*4 + (l15 & 3);
            #pragma unroll
            for (int rf = 0; rf < 4; ++rf){
                u32 v0 = hw_f8x4(lrelu(acc[rf][0]), lrelu(acc[rf][1]),
                                 lrelu(acc[rf][2]), lrelu(acc[rf][3]));
                u32 p1 = (u32)__shfl_xor((int)v0, 1, 64);
                u32 x  = (l15 & 1) ? __builtin_amdgcn_perm(p1, v0, 0x03070105u)
                                   : __builtin_amdgcn_perm(p1, v0, 0x06020400u);
                u32 p2 = (u32)__shfl_xor((int)x, 2, 64);
                u32 y  = (l15 & 2) ? __builtin_amdgcn_perm(p2, x, 0x03020706u)
                                   : __builtin_amdgcn_perm(p2, x, 0x05040100u);
                *(u32*)(sM + (rf*16 + rowsub)*144 + colbase) = y;
            }
        }
        __syncthreads();

        ptile = tile; pe_prev = pe_cur; rdv_prev = rdv_cur;
    }

    // drain: epilogue for the last tile
    if (ptile >= 0){
        int ep = ptile*64 + el;
        if (ep < E){
            int pp = __shfl(pe_prev, el*8, 64);
            uint4 v = *(const uint4*)(sM + el*144 + q*16);
            ((uint4*)m)[(size_t)pp*8 + q] = v;
            u32 ws[4] = {v.x, v.y, v.z, v.w};
            float dotv = 0.f;
            #pragma unroll
            for (int i = 0; i < 4; ++i){
                f32x2 fa = hw_f8_dec2(ws[i]);
                f32x2 fb = hw_f8_dec2_hi(ws[i]);
                const float* al = att_l + q*16 + i*4;
                dotv = fmaf(fa.x, al[0], dotv); dotv = fmaf(fa.y, al[1], dotv);
                dotv = fmaf(fb.x, al[2], dotv); dotv = fmaf(fb.y, al[3], dotv);
            }
            dotv += __shfl_xor(dotv, 1); dotv += __shfl_xor(dotv, 2); dotv += __shfl_xor(dotv, 4);
            if (q == 0) alpha[pp] = lrelu(dotv + __shfl(rdv_prev, el*8, 64));
        }
    }
}

// ---------------- K4+K5a fused: segment softmax-aggregate (fp8 m) -> LDS -> W2 MFMA -> fp8 Agru ----------------
__global__ __launch_bounds__(512, 2) void k_aggconv(
    const int* __restrict__ rs, const float* __restrict__ alpha, const u8* __restrict__ m,
    const u16* __restrict__ W2b, const float* __restrict__ bc,
    u8* __restrict__ Agru, int N)
{
    __shared__ __align__(16) u8 sA[64*272];   // bf16 aggregated rows (+16B pad)
    __shared__ __align__(16) u8 sO[64*272];   // bf16 conv output rows
    int t = threadIdx.x, w = t >> 6, lane = t & 63, l15 = lane & 15, l4 = lane >> 4;
    int tile = blockIdx.x;

    s16x8 bfr[4];                 // wave w owns cols [w*16, w*16+16)
    #pragma unroll
    for (int kf = 0; kf < 4; ++kf)
        bfr[kf] = *(const s16x8*)(W2b + (size_t)(w*16 + l15)*128 + kf*32 + l4*8);

    // ---- phase 1: each wave aggregates 8 nodes into sA ----
    #pragma unroll 1
    for (int i = 0; i < 8; ++i){
        int nloc = w*8 + i;
        int n = tile*64 + nloc;
        int s = rs[n], tend = rs[n+1];
        int deg = tend - s;
        float ax = 0.f, ay = 0.f;
        if (deg > 0 && deg <= 64){
            float av = -1e38f;
            if (lane < deg) av = alpha[s + lane];
            float mx = wave_max(av);
            float ev = (lane < deg) ? __expf(av - mx) : 0.f;
            float ssum = wave_sum(ev);
            float wreg = ev / ssum;
            int k = 0;
            for (; k + 2 <= deg; k += 2){
                float w0 = __shfl(wreg, k);
                float w1 = __shfl(wreg, k + 1);
                u32 u0 = *(const u16*)(m + (size_t)(s + k)*HD + 2*lane);
                u32 u1 = *(const u16*)(m + (size_t)(s + k + 1)*HD + 2*lane);
                f32x2 f0 = hw_f8_dec2(u0);
                f32x2 f1 = hw_f8_dec2(u1);
                ax = fmaf(w0, f0.x, ax); ay = fmaf(w0, f0.y, ay);
                ax = fmaf(w1, f1.x, ax); ay = fmaf(w1, f1.y, ay);
            }
            if (k < deg){
                float w0 = __shfl(wreg, k);
                u32 u0 = *(const u16*)(m + (size_t)(s + k)*HD + 2*lane);
                f32x2 f0 = hw_f8_dec2(u0);
                ax = fmaf(w0, f0.x, ax); ay = fmaf(w0, f0.y, ay);
            }
        } else if (deg > 64){
            float mx = -1e38f;
            for (int k = lane; k < deg; k += 64) mx = fmaxf(mx, alpha[s + k]);
            mx = wave_max(mx);
            float ssum = 0.f;
            for (int k = lane; k < deg; k += 64) ssum += __expf(alpha[s + k] - mx);
            ssum = wave_sum(ssum);
            float inv = 1.f / ssum;
            for (int k = 0; k < deg; ++k){
                float wgt = __expf(alpha[s + k] - mx) * inv;
                u32 u0 = *(const u16*)(m + (size_t)(s + k)*HD + 2*lane);
                f32x2 f0 = hw_f8_dec2(u0);
                ax = fmaf(wgt, f0.x, ax);
                ay = fmaf(wgt, f0.y, ay);
            }
        }
        *(u32*)(sA + nloc*272 + lane*4) = pk2(ax, ay);
    }
    __syncthreads();

    // ---- phase 2: W2 @ sA + bias, elu, -> sO ----
    f32x4 acc[4];
    #pragma unroll
    for (int rf = 0; rf < 4; ++rf) acc[rf] = (f32x4)0.f;
    #pragma unroll
    for (int kf = 0; kf < 4; ++kf){
        s16x8 av[4];
        #pragma unroll
        for (int rf = 0; rf < 4; ++rf)
            av[rf] = *(const s16x8*)(sA + (rf*16 + l15)*272 + kf*64 + l4*16);
        #pragma unroll
        for (int rf = 0; rf < 4; ++rf)
            acc[rf] = MFMA16(av[rf], bfr[kf], acc[rf]);
    }
    float b0 = bc[w*16 + l15];
    #pragma unroll
    for (int rf = 0; rf < 4; ++rf)
        #pragma unroll
        for (int r = 0; r < 4; ++r){
            int row = rf*16 + l4*4 + r;
            *(u16*)(sO + row*272 + (w*16 + l15)*2) = f32_to_bf16(eluf_(acc[rf][r] + b0));
        }
    __syncthreads();

    // ---- write Agru h-half fp8 (8 threads/row, 16 cols each) ----
    {
        int el = t >> 3, q = t & 7;
        size_t n = (size_t)tile*64 + el;
        uint4 v0 = *(const uint4*)(sO + el*272 + q*32);
        uint4 v1 = *(const uint4*)(sO + el*272 + q*32 + 16);
        uint4 p;
        p.x = hw_f8x4(bf16lo(v0.x), bf16hi(v0.x), bf16lo(v0.y), bf16hi(v0.y));
        p.y = hw_f8x4(bf16lo(v0.z), bf16hi(v0.z), bf16lo(v0.w), bf16hi(v0.w));
        p.z = hw_f8x4(bf16lo(v1.x), bf16hi(v1.x), bf16lo(v1.y), bf16hi(v1.y));
        p.w = hw_f8x4(bf16lo(v1.z), bf16hi(v1.z), bf16lo(v1.w), bf16hi(v1.w));
        *(uint4*)(Agru + n*256 + q*16) = p;            // h half (K<128)
    }
}

// ---------------- K5b (fp8 MFMA): GRU cell + fused LayerNorm -> out ----------------
__global__ __launch_bounds__(512, 4) void k_gru_mfma(
    const u8* __restrict__ Agru, const u16* __restrict__ xeb, const u8* __restrict__ Bgf8,
    const float* __restrict__ bih, const float* __restrict__ bhh,
    float* __restrict__ out, int N, int ntiles)
{
    __shared__ __align__(16) u8 sA[32*272];
    __shared__ __align__(16) u8 sX[32*272];
    __shared__ __align__(16) float sOut[32*132];
    int t = threadIdx.x, w = t >> 6, lane = t & 63, l15 = lane & 15, l4 = lane >> 4;

    i64_ bfr0[8], bfr1[8], bfr2[4], bfr3[4];
    {
        int jc = w*16 + l15;
        #pragma unroll
        for (int kf = 0; kf < 8; ++kf){
            bfr0[kf] = *(const i64_*)(Bgf8 + (size_t)(jc)*256       + kf*32 + l4*8);
            bfr1[kf] = *(const i64_*)(Bgf8 + (size_t)(128 + jc)*256 + kf*32 + l4*8);
        }
        #pragma unroll
        for (int kf = 0; kf < 4; ++kf){
            bfr2[kf] = *(const i64_*)(Bgf8 + (size_t)(256 + jc)*256 + kf*32 + l4*8);
            bfr3[kf] = *(const i64_*)(Bgf8 + (size_t)(384 + jc)*256 + (kf+4)*32 + l4*8);
        }
    }
    int j = w*16 + l15;
    float rb = bih[j] + bhh[j];
    float zb = bih[128 + j] + bhh[128 + j];
    float ib = bih[256 + j];
    float hb = bhh[256 + j];

    int el = t >> 4, part = t & 15;
    int stride = gridDim.x;
    int tile = blockIdx.x;
    uint4 pa, px;
    if (tile < ntiles){
        pa = *((const uint4*)Agru + ((size_t)tile*32 + el)*16 + part);
        px = *((const uint4*)xeb  + ((size_t)tile*32 + el)*16 + part);
    }

    for (; tile < ntiles; tile += stride){
        *(uint4*)(sA + el*272 + part*16) = pa;
        *(uint4*)(sX + el*272 + part*16) = px;
        __syncthreads();

        int nt = tile + stride;
        if (nt < ntiles){
            pa = *((const uint4*)Agru + ((size_t)nt*32 + el)*16 + part);
            px = *((const uint4*)xeb  + ((size_t)nt*32 + el)*16 + part);
        }

        f32x4 acc[2][4];
        #pragma unroll
        for (int rf = 0; rf < 2; ++rf)
            #pragma unroll
            for (int g = 0; g < 4; ++g) acc[rf][g] = (f32x4)0.f;
        #pragma unroll
        for (int kf = 0; kf < 8; ++kf){
            i64_ a0 = *(const i64_*)(sA + l15*272 + kf*32 + l4*8);
            i64_ a1 = *(const i64_*)(sA + (16 + l15)*272 + kf*32 + l4*8);
            acc[0][0] = MFMAF8(a0, bfr0[kf], acc[0][0]);
            acc[1][0] = MFMAF8(a1, bfr0[kf], acc[1][0]);
            acc[0][1] = MFMAF8(a0, bfr1[kf], acc[0][1]);
            acc[1][1] = MFMAF8(a1, bfr1[kf], acc[1][1]);
            if (kf < 4){
                acc[0][2] = MFMAF8(a0, bfr2[kf], acc[0][2]);
                acc[1][2] = MFMAF8(a1, bfr2[kf], acc[1][2]);
            } else {
                acc[0][3] = MFMAF8(a0, bfr3[kf-4], acc[0][3]);
                acc[1][3] = MFMAF8(a1, bfr3[kf-4], acc[1][3]);
            }
        }
        #pragma unroll
        for (int rf = 0; rf < 2; ++rf)
            #pragma unroll
            for (int r = 0; r < 4; ++r){
                int rl = rf*16 + l4*4 + r;
                float rr = sigmoidf_(acc[rf][0][r] + rb);
                float zz = sigmoidf_(acc[rf][1][r] + zb);
                float iv = acc[rf][2][r] + ib;
                float hv = acc[rf][3][r] + hb;
                float nc = tanhf_(iv + rr*hv);
                float xej = bf16f(*(const u16*)(sX + rl*272 + 2*j));
                float v = (1.f - zz)*nc + zz*xej;
                v = fmaxf(v, 0.f);
                sOut[rl*132 + j] = v;
            }
        __syncthreads();
        {
            int row = t >> 4, sub = t & 15;
            const float* rp = sOut + row*132 + sub*8;
            float v0 = rp[0], v1 = rp[1], v2 = rp[2], v3 = rp[3];
            float v4 = rp[4], v5 = rp[5], v6 = rp[6], v7 = rp[7];
            float s1 = v0+v1+v2+v3+v4+v5+v6+v7;
            float s2 = v0*v0+v1*v1+v2*v2+v3*v3+v4*v4+v5*v5+v6*v6+v7*v7;
            #pragma unroll
            for (int o = 1; o < 16; o <<= 1){ s1 += __shfl_xor(s1, o); s2 += __shfl_xor(s2, o); }
            float mu  = s1 * (1.f/128.f);
            float var = s2 * (1.f/128.f) - mu*mu;
            var = fmaxf(var, 0.f);
            float rsd = rsqrtf(var + 1e-5f);
            float* op = out + ((size_t)tile*32 + row)*128 + sub*8;
            float4 o0, o1;
            o0.x = (v0-mu)*rsd; o0.y = (v1-mu)*rsd; o0.z = (v2-mu)*rsd; o0.w = (v3-mu)*rsd;
            o1.x = (v4-mu)*rsd; o1.y = (v5-mu)*rsd; o1.z = (v6-mu)*rsd; o1.w = (v7-mu)*rsd;
            ((float4*)op)[0] = o0; ((float4*)op)[1] = o1;
        }
        __syncthreads();
    }
}

// ---------------- host ----------------
extern "C" void kernel_launch(void* const* d_in, const int* in_sizes, int n_in,
                              void* d_out, int out_size, void* d_ws, size_t ws_size,
                              hipStream_t stream)
{
    const float* x       = (const float*)d_in[0];
    const float* ea      = (const float*)d_in[1];
    const float* W_enter = (const float*)d_in[2];
    const float* b_enter = (const float*)d_in[3];
    const float* W1      = (const float*)d_in[4];
    const float* att_l   = (const float*)d_in[5];
    const float* att_r   = (const float*)d_in[6];
    const float* W2      = (const float*)d_in[7];
    const float* b_conv  = (const float*)d_in[8];
    const float* W_ih    = (const float*)d_in[9];
    const float* W_hh    = (const float*)d_in[10];
    const float* b_ih    = (const float*)d_in[11];
    const float* b_hh    = (const float*)d_in[12];
    const int*   eidx    = (const int*)d_in[13];

    int N = in_sizes[0] / DIN;
    int E = in_sizes[13] / 2;
    const int* src = eidx;
    const int* dst = eidx + E;
    float* out = (float*)d_out;

    size_t off = 0;
    char* base = (char*)d_ws;
    auto alloc = [&](size_t bytes) -> char* {
        char* p = base + off;
        off = (off + bytes + 255) & ~(size_t)255;
        return p;
    };
    u16*   xeb   = (u16*)  alloc((size_t)N*HD*2);
    u8*    Agru  = (u8*)   alloc((size_t)N*256);
    float* r_dst = (float*)alloc((size_t)N*4);
    float* alpha = (float*)alloc((size_t)E*4);
    int*   deg   = (int*)  alloc((size_t)N*4);
    int*   rs    = (int*)  alloc((size_t)(N+1)*4);
    int*   cnt   = (int*)  alloc((size_t)N*4);
    int*   btot  = (int*)  alloc(1024);
    int*   bbase = (int*)  alloc(1024);
    u16*   W1b   = (u16*)  alloc(20480*2);
    u16*   W2b   = (u16*)  alloc(16384*2);
    u16*   Wentb = (u16*)  alloc(8192*2);
    u8*    Bgf8  = (u8*)   alloc(131072);
    u8*    mbuf  = (u8*)   alloc((size_t)E*HD);

    int ntiles_n64 = N/64, ntiles_e = (E + 63)/64, ntiles_g = N/32;

    k_prep   <<<(176128+255)/256, 256, 0, stream>>>(W1, W2, W_enter, W_ih, W_hh, W1b, W2b, Wentb, Bgf8);
    hipMemsetAsync(deg, 0, (size_t)N*4, stream);
    hipMemsetAsync(cnt, 0, (size_t)N*4, stream);
    k_enter_mfma<<<ntiles_n64, 256, 0, stream>>>(x, Wentb, b_enter, att_r, xeb, Agru, r_dst, N);
    k_hist   <<<(E+255)/256, 256, 0, stream>>>(dst, deg, E);
    k_scan_a <<<N/1024, 256, 0, stream>>>(deg, rs, btot, N);
    k_scan_b <<<1, 256, 0, stream>>>(btot, bbase);
    k_scan_c <<<(N+255)/256, 256, 0, stream>>>(rs, bbase, N, E);
    k_edge_mfma<<<1024, 512, 0, stream>>>(xeb, ea, W1b, att_l, r_dst, src, dst, rs, cnt,
                                          mbuf, alpha, ntiles_e, E);
    k_aggconv<<<ntiles_n64, 512, 0, stream>>>(rs, alpha, mbuf, W2b, b_conv, Agru, N);
    k_gru_mfma  <<<2048, 512, 0, stream>>>(Agru, xeb, Bgf8, b_ih, b_hh, out, N, ntiles_g);
}

// Round 13
// 524.627 us; speedup vs baseline: 1.0065x; 1.0065x over previous
//
#include <hip/hip_runtime.h>
#include <stdint.h>

#define HD  128
#define DIN 64
#define DE  32

typedef unsigned int u32; typedef unsigned short u16; typedef unsigned char u8;
typedef long i64_;
typedef short s16x8 __attribute__((ext_vector_type(8)));
typedef float f32x4 __attribute__((ext_vector_type(4)));
typedef float f32x2 __attribute__((ext_vector_type(2)));

#define MFMA16(a,b,c)  __builtin_amdgcn_mfma_f32_16x16x32_bf16((a),(b),(c),0,0,0)
#define MFMAF8(a,b,c)  __builtin_amdgcn_mfma_f32_16x16x32_fp8_fp8((a),(b),(c),0,0,0)

__device__ __forceinline__ float lrelu(float x){ return x > 0.f ? x : 0.01f*x; }
__device__ __forceinline__ float sigmoidf_(float x){ return 1.f/(1.f + __expf(-x)); }
__device__ __forceinline__ float tanhf_(float x){
    float t = fminf(fmaxf(x, -15.f), 15.f);
    float e = __expf(2.f*t);
    return (e - 1.f)/(e + 1.f);
}
__device__ __forceinline__ float eluf_(float x){ return x > 0.f ? x : expm1f(x); }

__device__ __forceinline__ u16 f32_to_bf16(float x){
    u32 u = __float_as_uint(x);
    u += 0x7FFFu + ((u >> 16) & 1u);
    return (u16)(u >> 16);
}
__device__ __forceinline__ float bf16lo(u32 u){ return __uint_as_float((u & 0xFFFFu) << 16); }
__device__ __forceinline__ float bf16hi(u32 u){ return __uint_as_float(u & 0xFFFF0000u); }
__device__ __forceinline__ float bf16f(u16 h){ return __uint_as_float(((u32)h) << 16); }
__device__ __forceinline__ u32 pk2(float a, float b){
    return (u32)f32_to_bf16(a) | ((u32)f32_to_bf16(b) << 16);
}
// HW OCP e4m3fn converters (gfx950)
__device__ __forceinline__ u8 hw_f8(float v){
    return (u8)__builtin_amdgcn_cvt_pk_fp8_f32(v, v, 0, false);
}
__device__ __forceinline__ u32 hw_f8x4(float a, float b, float c, float d){
    u32 r = (u32)__builtin_amdgcn_cvt_pk_fp8_f32(a, b, 0, false);
    r = (u32)__builtin_amdgcn_cvt_pk_fp8_f32(c, d, (int)r, true);
    return r;
}
__device__ __forceinline__ f32x2 hw_f8_dec2(u32 u){   // decodes bytes [0:1]
    return __builtin_amdgcn_cvt_pk_f32_fp8((int)u, false);
}
__device__ __forceinline__ f32x2 hw_f8_dec2_hi(u32 u){ // decodes bytes [2:3]
    return __builtin_amdgcn_cvt_pk_f32_fp8((int)u, true);
}

__device__ __forceinline__ float wave_max(float v){
    #pragma unroll
    for (int o = 32; o > 0; o >>= 1) v = fmaxf(v, __shfl_xor(v, o, 64));
    return v;
}
__device__ __forceinline__ float wave_sum(float v){
    #pragma unroll
    for (int o = 32; o > 0; o >>= 1) v += __shfl_xor(v, o, 64);
    return v;
}

// ---------------- weight prep: fp32 -> bf16 (+ fp8 GRU B-pack) ----------------
__global__ void k_prep(const float* __restrict__ W1, const float* __restrict__ W2,
                       const float* __restrict__ Went,
                       const float* __restrict__ Wih, const float* __restrict__ Whh,
                       u16* __restrict__ W1b, u16* __restrict__ W2b,
                       u16* __restrict__ Wentb, u8* __restrict__ Bgf8)
{
    int i = blockIdx.x*256 + threadIdx.x;
    if (i < 20480){ W1b[i] = f32_to_bf16(W1[i]); return; }
    i -= 20480;
    if (i < 16384){ W2b[i] = f32_to_bf16(W2[i]); return; }
    i -= 16384;
    if (i < 8192){ Wentb[i] = f32_to_bf16(Went[i]); return; }
    i -= 8192;
    if (i < 131072){
        int col = i >> 8, k = i & 255;
        int g = col >> 7, j = col & 127;
        float v;
        if      (g == 0) v = (k < 128) ? Wih[j*128 + k]        : Whh[j*128 + k - 128];
        else if (g == 1) v = (k < 128) ? Wih[(128+j)*128 + k]  : Whh[(128+j)*128 + k - 128];
        else if (g == 2) v = (k < 128) ? Wih[(256+j)*128 + k]  : 0.f;
        else             v = (k < 128) ? 0.f                   : Whh[(256+j)*128 + k - 128];
        Bgf8[i] = hw_f8(v);
    }
}

// ---------------- K1 (MFMA): xeb = bf16(lrelu(x@W^T+b)); Agru xe-half fp8; r_dst ----------------
__global__ __launch_bounds__(256, 4) void k_enter_mfma(
    const float* __restrict__ x, const u16* __restrict__ Wb, const float* __restrict__ be,
    const float* __restrict__ att_r, u16* __restrict__ xeb, u8* __restrict__ Agru,
    float* __restrict__ r_out, int N)
{
    __shared__ __align__(16) u8 sA[64*144];
    __shared__ __align__(16) u8 sO[64*272];
    int t = threadIdx.x, w = t >> 6, lane = t & 63, l15 = lane & 15, l4 = lane >> 4;
    int tile = blockIdx.x;

    s16x8 bfr[2][2];
    #pragma unroll
    for (int kf = 0; kf < 2; ++kf)
        #pragma unroll
        for (int cf = 0; cf < 2; ++cf)
            bfr[kf][cf] = *(const s16x8*)(Wb + (size_t)(w*32 + cf*16 + l15)*64 + kf*32 + l4*8);

    int el = t >> 2, q = t & 3;
    size_t n = (size_t)tile*64 + el;
    {
        const float4* xs = (const float4*)(x + n*64 + q*16);
        float4 f0 = xs[0], f1 = xs[1], f2 = xs[2], f3 = xs[3];
        uint4 o0, o1;
        o0.x = pk2(f0.x,f0.y); o0.y = pk2(f0.z,f0.w); o0.z = pk2(f1.x,f1.y); o0.w = pk2(f1.z,f1.w);
        o1.x = pk2(f2.x,f2.y); o1.y = pk2(f2.z,f2.w); o1.z = pk2(f3.x,f3.y); o1.w = pk2(f3.z,f3.w);
        *(uint4*)(sA + el*144 + q*32)      = o0;
        *(uint4*)(sA + el*144 + q*32 + 16) = o1;
    }
    __syncthreads();

    f32x4 acc[4][2];
    #pragma unroll
    for (int rf = 0; rf < 4; ++rf){ acc[rf][0] = (f32x4)0.f; acc[rf][1] = (f32x4)0.f; }
    #pragma unroll
    for (int kf = 0; kf < 2; ++kf){
        s16x8 a[4];
        #pragma unroll
        for (int rf = 0; rf < 4; ++rf)
            a[rf] = *(const s16x8*)(sA + (rf*16 + l15)*144 + kf*64 + l4*16);
        #pragma unroll
        for (int rf = 0; rf < 4; ++rf){
            acc[rf][0] = MFMA16(a[rf], bfr[kf][0], acc[rf][0]);
            acc[rf][1] = MFMA16(a[rf], bfr[kf][1], acc[rf][1]);
        }
    }
    float b0 = be[w*32 + l15], b1 = be[w*32 + 16 + l15];
    #pragma unroll
    for (int rf = 0; rf < 4; ++rf)
        #pragma unroll
        for (int r = 0; r < 4; ++r){
            int row = rf*16 + l4*4 + r;
            *(u16*)(sO + row*272 + (w*32 + l15)*2)      = f32_to_bf16(lrelu(acc[rf][0][r] + b0));
            *(u16*)(sO + row*272 + (w*32 + 16 + l15)*2) = f32_to_bf16(lrelu(acc[rf][1][r] + b1));
        }
    __syncthreads();

    float dot = 0.f;
    #pragma unroll
    for (int i = 0; i < 4; ++i){
        uint4 v = *(const uint4*)(sO + el*272 + q*64 + 16*i);
        ((uint4*)xeb)[n*16 + q*4 + i] = v;
        float f0 = bf16lo(v.x), f1 = bf16hi(v.x), f2 = bf16lo(v.y), f3 = bf16hi(v.y);
        float f4 = bf16lo(v.z), f5 = bf16hi(v.z), f6 = bf16lo(v.w), f7 = bf16hi(v.w);
        const float* al = att_r + q*32 + 8*i;
        dot = fmaf(f0, al[0], dot); dot = fmaf(f1, al[1], dot);
        dot = fmaf(f2, al[2], dot); dot = fmaf(f3, al[3], dot);
        dot = fmaf(f4, al[4], dot); dot = fmaf(f5, al[5], dot);
        dot = fmaf(f6, al[6], dot); dot = fmaf(f7, al[7], dot);
        uint2 p; p.x = hw_f8x4(f0, f1, f2, f3); p.y = hw_f8x4(f4, f5, f6, f7);
        *(uint2*)(Agru + n*256 + 128 + q*32 + i*8) = p;   // xe half (K>=128)
    }
    dot += __shfl_xor(dot, 1); dot += __shfl_xor(dot, 2);
    if (q == 0) r_out[n] = dot;
}

// ---------------- CSR build ----------------
__global__ void k_hist(const int* __restrict__ dst, int* __restrict__ deg, int E){
    int e = blockIdx.x*256 + threadIdx.x;
    if (e < E) atomicAdd(&deg[dst[e]], 1);
}
__global__ __launch_bounds__(256) void k_scan_a(
    const int* __restrict__ deg, int* __restrict__ rs, int* __restrict__ btot, int N)
{
    __shared__ int sd[256];
    int b = blockIdx.x, t = threadIdx.x;
    int base = b*1024 + t*4;
    int d0 = deg[base], d1 = deg[base+1], d2 = deg[base+2], d3 = deg[base+3];
    int s = d0 + d1 + d2 + d3;
    sd[t] = s; __syncthreads();
    for (int o = 1; o < 256; o <<= 1){
        int v = (t >= o) ? sd[t-o] : 0;
        __syncthreads();
        sd[t] += v;
        __syncthreads();
    }
    int ex = sd[t] - s;
    rs[base]   = ex;
    rs[base+1] = ex + d0;
    rs[base+2] = ex + d0 + d1;
    rs[base+3] = ex + d0 + d1 + d2;
    if (t == 0) btot[b] = sd[255];
}
__global__ __launch_bounds__(256) void k_scan_b(const int* __restrict__ btot, int* __restrict__ bbase){
    __shared__ int sd[256];
    int t = threadIdx.x;
    int s = btot[t];
    sd[t] = s; __syncthreads();
    for (int o = 1; o < 256; o <<= 1){
        int v = (t >= o) ? sd[t-o] : 0;
        __syncthreads();
        sd[t] += v;
        __syncthreads();
    }
    bbase[t] = sd[t] - s;
}
__global__ void k_scan_c(int* __restrict__ rs, const int* __restrict__ bbase, int N, int E){
    int i = blockIdx.x*256 + threadIdx.x;
    if (i < N) rs[i] += bbase[i >> 10];
    if (i == 0) rs[N] = E;
}
__global__ void k_scatter(const int* __restrict__ dst, const int* __restrict__ rs,
                          int* __restrict__ cnt, int* __restrict__ epos, int E){
    int e = blockIdx.x*256 + threadIdx.x;
    if (e >= E) return;
    int d = dst[e];
    int pos = rs[d] + atomicAdd(&cnt[d], 1);
    epos[e] = pos;
}

// ---------------- K2 (MFMA, 8-wave, 2-barrier pipeline, HW fp8) ----------------
__global__ __launch_bounds__(512, 4) void k_edge_mfma(
    const u16* __restrict__ xeb, const float* __restrict__ ea,
    const u16* __restrict__ W1b, const float* __restrict__ att_l,
    const float* __restrict__ r_dst, const int* __restrict__ src, const int* __restrict__ dst,
    const int* __restrict__ epos,
    u8* __restrict__ m, float* __restrict__ alpha, int ntiles, int E)
{
    __shared__ __align__(16) u8 sA[64*336];
    __shared__ __align__(16) u8 sM[64*144];
    int t = threadIdx.x, w = t >> 6, lane = t & 63, l15 = lane & 15, l4 = lane >> 4;

    s16x8 bfr[5];                 // wave w owns cols [w*16, w*16+16)
    #pragma unroll
    for (int kf = 0; kf < 5; ++kf)
        bfr[kf] = *(const s16x8*)(W1b + (size_t)(w*16 + l15)*160 + kf*32 + l4*8);

    int el = t >> 3, q = t & 7;   // 64 edges/tile, 8 threads/edge
    int stride = gridDim.x;
    int tile = blockIdx.x;

    uint4 cx0, cx1;
    u32 ce0, ce1;
    int   pe = 0;
    float rdv = 0.f;
    {
        int e = tile*64 + el;
        if (tile < ntiles && e < E){
            int sn = src[e];
            const uint4* xs = (const uint4*)xeb + (size_t)sn*16 + q*2;
            cx0 = xs[0]; cx1 = xs[1];
            float4 f = *(const float4*)(ea + (size_t)e*32 + q*4);
            ce0 = pk2(f.x, f.y); ce1 = pk2(f.z, f.w);
            pe  = epos[e];
            rdv = r_dst[dst[e]];
        }
    }

    int   ptile = -1;
    int   pe_prev = 0;
    float rdv_prev = 0.f;

    for (; tile < ntiles; tile += stride){
        int e = tile*64 + el;
        if (e < E){
            uint4* d = (uint4*)(sA + el*336 + q*32);
            d[0] = cx0; d[1] = cx1;
            *(u32*)(sA + el*336 + 256 + q*8)     = ce0;
            *(u32*)(sA + el*336 + 256 + q*8 + 4) = ce1;
        }
        int pe_cur = pe; float rdv_cur = rdv;

        int nt = tile + stride;
        if (nt < ntiles){
            int e2 = nt*64 + el;
            if (e2 < E){
                int sn = src[e2];
                const uint4* xs = (const uint4*)xeb + (size_t)sn*16 + q*2;
                cx0 = xs[0]; cx1 = xs[1];
                float4 f = *(const float4*)(ea + (size_t)e2*32 + q*4);
                ce0 = pk2(f.x, f.y); ce1 = pk2(f.z, f.w);
                pe  = epos[e2];
                rdv = r_dst[dst[e2]];
            }
        }

        // epilogue for previous tile (reads sM written last iteration)
        if (ptile >= 0){
            int ep = ptile*64 + el;
            if (ep < E){
                uint4 v = *(const uint4*)(sM + el*144 + q*16);
                ((uint4*)m)[(size_t)pe_prev*8 + q] = v;
                u32 ws[4] = {v.x, v.y, v.z, v.w};
                float dotv = 0.f;
                #pragma unroll
                for (int i = 0; i < 4; ++i){
                    f32x2 fa = hw_f8_dec2(ws[i]);
                    f32x2 fb = hw_f8_dec2_hi(ws[i]);
                    const float* al = att_l + q*16 + i*4;
                    dotv = fmaf(fa.x, al[0], dotv); dotv = fmaf(fa.y, al[1], dotv);
                    dotv = fmaf(fb.x, al[2], dotv); dotv = fmaf(fb.y, al[3], dotv);
                }
                dotv += __shfl_xor(dotv, 1); dotv += __shfl_xor(dotv, 2); dotv += __shfl_xor(dotv, 4);
                if (q == 0) alpha[pe_prev] = lrelu(dotv + rdv_prev);
            }
        }
        __syncthreads();

        f32x4 acc[4];
        #pragma unroll
        for (int rf = 0; rf < 4; ++rf) acc[rf] = (f32x4)0.f;
        #pragma unroll
        for (int kf = 0; kf < 5; ++kf){
            s16x8 a[4];
            #pragma unroll
            for (int rf = 0; rf < 4; ++rf)
                a[rf] = *(const s16x8*)(sA + (rf*16 + l15)*336 + kf*64 + l4*16);
            #pragma unroll
            for (int rf = 0; rf < 4; ++rf)
                acc[rf] = MFMA16(a[rf], bfr[kf], acc[rf]);
        }

        int col = w*16 + l15;
        #pragma unroll
        for (int rf = 0; rf < 4; ++rf)
            #pragma unroll
            for (int r = 0; r < 4; ++r){
                int row = rf*16 + l4*4 + r;
                sM[row*144 + col] = hw_f8(lrelu(acc[rf][r]));
            }
        __syncthreads();

        ptile = tile; pe_prev = pe_cur; rdv_prev = rdv_cur;
    }

    if (ptile >= 0){
        int ep = ptile*64 + el;
        if (ep < E){
            uint4 v = *(const uint4*)(sM + el*144 + q*16);
            ((uint4*)m)[(size_t)pe_prev*8 + q] = v;
            u32 ws[4] = {v.x, v.y, v.z, v.w};
            float dotv = 0.f;
            #pragma unroll
            for (int i = 0; i < 4; ++i){
                f32x2 fa = hw_f8_dec2(ws[i]);
                f32x2 fb = hw_f8_dec2_hi(ws[i]);
                const float* al = att_l + q*16 + i*4;
                dotv = fmaf(fa.x, al[0], dotv); dotv = fmaf(fa.y, al[1], dotv);
                dotv = fmaf(fb.x, al[2], dotv); dotv = fmaf(fb.y, al[3], dotv);
            }
            dotv += __shfl_xor(dotv, 1); dotv += __shfl_xor(dotv, 2); dotv += __shfl_xor(dotv, 4);
            if (q == 0) alpha[pe_prev] = lrelu(dotv + rdv_prev);
        }
    }
}

// ---------------- K4+K5a fused: segment softmax-aggregate (fp8 m) -> LDS -> W2 MFMA -> fp8 Agru ----------------
__global__ __launch_bounds__(512, 4) void k_aggconv(
    const int* __restrict__ rs, const float* __restrict__ alpha, const u8* __restrict__ m,
    const u16* __restrict__ W2b, const float* __restrict__ bc,
    u8* __restrict__ Agru, int N)
{
    __shared__ __align__(16) u8 sA[64*272];   // bf16 aggregated rows (+16B pad)
    __shared__ __align__(16) u8 sO[64*272];   // bf16 conv output rows
    int t = threadIdx.x, w = t >> 6, lane = t & 63, l15 = lane & 15, l4 = lane >> 4;
    int tile = blockIdx.x;

    s16x8 bfr[4];                 // wave w owns cols [w*16, w*16+16)
    #pragma unroll
    for (int kf = 0; kf < 4; ++kf)
        bfr[kf] = *(const s16x8*)(W2b + (size_t)(w*16 + l15)*128 + kf*32 + l4*8);

    // ---- phase 1: each wave aggregates 8 nodes into sA ----
    #pragma unroll 1
    for (int i = 0; i < 8; ++i){
        int nloc = w*8 + i;
        int n = tile*64 + nloc;
        int s = rs[n], tend = rs[n+1];
        int deg = tend - s;
        float ax = 0.f, ay = 0.f;
        if (deg > 0 && deg <= 64){
            float av = -1e38f;
            if (lane < deg) av = alpha[s + lane];
            float mx = wave_max(av);
            float ev = (lane < deg) ? __expf(av - mx) : 0.f;
            float ssum = wave_sum(ev);
            float wreg = ev / ssum;
            int k = 0;
            for (; k + 2 <= deg; k += 2){
                float w0 = __shfl(wreg, k);
                float w1 = __shfl(wreg, k + 1);
                u32 u0 = *(const u16*)(m + (size_t)(s + k)*HD + 2*lane);
                u32 u1 = *(const u16*)(m + (size_t)(s + k + 1)*HD + 2*lane);
                f32x2 f0 = hw_f8_dec2(u0);
                f32x2 f1 = hw_f8_dec2(u1);
                ax = fmaf(w0, f0.x, ax); ay = fmaf(w0, f0.y, ay);
                ax = fmaf(w1, f1.x, ax); ay = fmaf(w1, f1.y, ay);
            }
            if (k < deg){
                float w0 = __shfl(wreg, k);
                u32 u0 = *(const u16*)(m + (size_t)(s + k)*HD + 2*lane);
                f32x2 f0 = hw_f8_dec2(u0);
                ax = fmaf(w0, f0.x, ax); ay = fmaf(w0, f0.y, ay);
            }
        } else if (deg > 64){
            float mx = -1e38f;
            for (int k = lane; k < deg; k += 64) mx = fmaxf(mx, alpha[s + k]);
            mx = wave_max(mx);
            float ssum = 0.f;
            for (int k = lane; k < deg; k += 64) ssum += __expf(alpha[s + k] - mx);
            ssum = wave_sum(ssum);
            float inv = 1.f / ssum;
            for (int k = 0; k < deg; ++k){
                float wgt = __expf(alpha[s + k] - mx) * inv;
                u32 u0 = *(const u16*)(m + (size_t)(s + k)*HD + 2*lane);
                f32x2 f0 = hw_f8_dec2(u0);
                ax = fmaf(wgt, f0.x, ax);
                ay = fmaf(wgt, f0.y, ay);
            }
        }
        *(u32*)(sA + nloc*272 + lane*4) = pk2(ax, ay);
    }
    __syncthreads();

    // ---- phase 2: W2 @ sA + bias, elu, -> sO ----
    f32x4 acc[4];
    #pragma unroll
    for (int rf = 0; rf < 4; ++rf) acc[rf] = (f32x4)0.f;
    #pragma unroll
    for (int kf = 0; kf < 4; ++kf){
        s16x8 av[4];
        #pragma unroll
        for (int rf = 0; rf < 4; ++rf)
            av[rf] = *(const s16x8*)(sA + (rf*16 + l15)*272 + kf*64 + l4*16);
        #pragma unroll
        for (int rf = 0; rf < 4; ++rf)
            acc[rf] = MFMA16(av[rf], bfr[kf], acc[rf]);
    }
    float b0 = bc[w*16 + l15];
    #pragma unroll
    for (int rf = 0; rf < 4; ++rf)
        #pragma unroll
        for (int r = 0; r < 4; ++r){
            int row = rf*16 + l4*4 + r;
            *(u16*)(sO + row*272 + (w*16 + l15)*2) = f32_to_bf16(eluf_(acc[rf][r] + b0));
        }
    __syncthreads();

    // ---- write Agru h-half fp8 (8 threads/row, 16 cols each) ----
    {
        int el = t >> 3, q = t & 7;
        size_t n = (size_t)tile*64 + el;
        uint4 v0 = *(const uint4*)(sO + el*272 + q*32);
        uint4 v1 = *(const uint4*)(sO + el*272 + q*32 + 16);
        uint4 p;
        p.x = hw_f8x4(bf16lo(v0.x), bf16hi(v0.x), bf16lo(v0.y), bf16hi(v0.y));
        p.y = hw_f8x4(bf16lo(v0.z), bf16hi(v0.z), bf16lo(v0.w), bf16hi(v0.w));
        p.z = hw_f8x4(bf16lo(v1.x), bf16hi(v1.x), bf16lo(v1.y), bf16hi(v1.y));
        p.w = hw_f8x4(bf16lo(v1.z), bf16hi(v1.z), bf16lo(v1.w), bf16hi(v1.w));
        *(uint4*)(Agru + n*256 + q*16) = p;            // h half (K<128)
    }
}

// ---------------- K5b (fp8 MFMA): GRU cell + fused LayerNorm -> out ----------------
__global__ __launch_bounds__(512, 4) void k_gru_mfma(
    const u8* __restrict__ Agru, const u16* __restrict__ xeb, const u8* __restrict__ Bgf8,
    const float* __restrict__ bih, const float* __restrict__ bhh,
    float* __restrict__ out, int N, int ntiles)
{
    __shared__ __align__(16) u8 sA[32*272];
    __shared__ __align__(16) u8 sX[32*272];
    __shared__ __align__(16) float sOut[32*132];
    int t = threadIdx.x, w = t >> 6, lane = t & 63, l15 = lane & 15, l4 = lane >> 4;

    i64_ bfr0[8], bfr1[8], bfr2[4], bfr3[4];
    {
        int jc = w*16 + l15;
        #pragma unroll
        for (int kf = 0; kf < 8; ++kf){
            bfr0[kf] = *(const i64_*)(Bgf8 + (size_t)(jc)*256       + kf*32 + l4*8);
            bfr1[kf] = *(const i64_*)(Bgf8 + (size_t)(128 + jc)*256 + kf*32 + l4*8);
        }
        #pragma unroll
        for (int kf = 0; kf < 4; ++kf){
            bfr2[kf] = *(const i64_*)(Bgf8 + (size_t)(256 + jc)*256 + kf*32 + l4*8);
            bfr3[kf] = *(const i64_*)(Bgf8 + (size_t)(384 + jc)*256 + (kf+4)*32 + l4*8);
        }
    }
    int j = w*16 + l15;
    float rb = bih[j] + bhh[j];
    float zb = bih[128 + j] + bhh[128 + j];
    float ib = bih[256 + j];
    float hb = bhh[256 + j];

    int el = t >> 4, part = t & 15;
    int stride = gridDim.x;
    int tile = blockIdx.x;
    uint4 pa, px;
    if (tile < ntiles){
        pa = *((const uint4*)Agru + ((size_t)tile*32 + el)*16 + part);
        px = *((const uint4*)xeb  + ((size_t)tile*32 + el)*16 + part);
    }

    for (; tile < ntiles; tile += stride){
        *(uint4*)(sA + el*272 + part*16) = pa;
        *(uint4*)(sX + el*272 + part*16) = px;
        __syncthreads();

        int nt = tile + stride;
        if (nt < ntiles){
            pa = *((const uint4*)Agru + ((size_t)nt*32 + el)*16 + part);
            px = *((const uint4*)xeb  + ((size_t)nt*32 + el)*16 + part);
        }

        f32x4 acc[2][4];
        #pragma unroll
        for (int rf = 0; rf < 2; ++rf)
            #pragma unroll
            for (int g = 0; g < 4; ++g) acc[rf][g] = (f32x4)0.f;
        #pragma unroll
        for (int kf = 0; kf < 8; ++kf){
            i64_ a0 = *(const i64_*)(sA + l15*272 + kf*32 + l4*8);
            i64_ a1 = *(const i64_*)(sA + (16 + l15)*272 + kf*32 + l4*8);
            acc[0][0] = MFMAF8(a0, bfr0[kf], acc[0][0]);
            acc[1][0] = MFMAF8(a1, bfr0[kf], acc[1][0]);
            acc[0][1] = MFMAF8(a0, bfr1[kf], acc[0][1]);
            acc[1][1] = MFMAF8(a1, bfr1[kf], acc[1][1]);
            if (kf < 4){
                acc[0][2] = MFMAF8(a0, bfr2[kf], acc[0][2]);
                acc[1][2] = MFMAF8(a1, bfr2[kf], acc[1][2]);
            } else {
                acc[0][3] = MFMAF8(a0, bfr3[kf-4], acc[0][3]);
                acc[1][3] = MFMAF8(a1, bfr3[kf-4], acc[1][3]);
            }
        }
        #pragma unroll
        for (int rf = 0; rf < 2; ++rf)
            #pragma unroll
            for (int r = 0; r < 4; ++r){
                int rl = rf*16 + l4*4 + r;
                float rr = sigmoidf_(acc[rf][0][r] + rb);
                float zz = sigmoidf_(acc[rf][1][r] + zb);
                float iv = acc[rf][2][r] + ib;
                float hv = acc[rf][3][r] + hb;
                float nc = tanhf_(iv + rr*hv);
                float xej = bf16f(*(const u16*)(sX + rl*272 + 2*j));
                float v = (1.f - zz)*nc + zz*xej;
                v = fmaxf(v, 0.f);
                sOut[rl*132 + j] = v;
            }
        __syncthreads();
        {
            int row = t >> 4, sub = t & 15;
            const float* rp = sOut + row*132 + sub*8;
            float v0 = rp[0], v1 = rp[1], v2 = rp[2], v3 = rp[3];
            float v4 = rp[4], v5 = rp[5], v6 = rp[6], v7 = rp[7];
            float s1 = v0+v1+v2+v3+v4+v5+v6+v7;
            float s2 = v0*v0+v1*v1+v2*v2+v3*v3+v4*v4+v5*v5+v6*v6+v7*v7;
            #pragma unroll
            for (int o = 1; o < 16; o <<= 1){ s1 += __shfl_xor(s1, o); s2 += __shfl_xor(s2, o); }
            float mu  = s1 * (1.f/128.f);
            float var = s2 * (1.f/128.f) - mu*mu;
            var = fmaxf(var, 0.f);
            float rsd = rsqrtf(var + 1e-5f);
            float* op = out + ((size_t)tile*32 + row)*128 + sub*8;
            float4 o0, o1;
            o0.x = (v0-mu)*rsd; o0.y = (v1-mu)*rsd; o0.z = (v2-mu)*rsd; o0.w = (v3-mu)*rsd;
            o1.x = (v4-mu)*rsd; o1.y = (v5-mu)*rsd; o1.z = (v6-mu)*rsd; o1.w = (v7-mu)*rsd;
            ((float4*)op)[0] = o0; ((float4*)op)[1] = o1;
        }
        __syncthreads();
    }
}

// ---------------- host ----------------
extern "C" void kernel_launch(void* const* d_in, const int* in_sizes, int n_in,
                              void* d_out, int out_size, void* d_ws, size_t ws_size,
                              hipStream_t stream)
{
    const float* x       = (const float*)d_in[0];
    const float* ea      = (const float*)d_in[1];
    const float* W_enter = (const float*)d_in[2];
    const float* b_enter = (const float*)d_in[3];
    const float* W1      = (const float*)d_in[4];
    const float* att_l   = (const float*)d_in[5];
    const float* att_r   = (const float*)d_in[6];
    const float* W2      = (const float*)d_in[7];
    const float* b_conv  = (const float*)d_in[8];
    const float* W_ih    = (const float*)d_in[9];
    const float* W_hh    = (const float*)d_in[10];
    const float* b_ih    = (const float*)d_in[11];
    const float* b_hh    = (const float*)d_in[12];
    const int*   eidx    = (const int*)d_in[13];

    int N = in_sizes[0] / DIN;
    int E = in_sizes[13] / 2;
    const int* src = eidx;
    const int* dst = eidx + E;
    float* out = (float*)d_out;

    size_t off = 0;
    char* base = (char*)d_ws;
    auto alloc = [&](size_t bytes) -> char* {
        char* p = base + off;
        off = (off + bytes + 255) & ~(size_t)255;
        return p;
    };
    u16*   xeb   = (u16*)  alloc((size_t)N*HD*2);
    u8*    Agru  = (u8*)   alloc((size_t)N*256);
    float* r_dst = (float*)alloc((size_t)N*4);
    float* alpha = (float*)alloc((size_t)E*4);
    int*   deg   = (int*)  alloc((size_t)N*4);
    int*   rs    = (int*)  alloc((size_t)(N+1)*4);
    int*   cnt   = (int*)  alloc((size_t)N*4);
    int*   epos  = (int*)  alloc((size_t)E*4);
    int*   btot  = (int*)  alloc(1024);
    int*   bbase = (int*)  alloc(1024);
    u16*   W1b   = (u16*)  alloc(20480*2);
    u16*   W2b   = (u16*)  alloc(16384*2);
    u16*   Wentb = (u16*)  alloc(8192*2);
    u8*    Bgf8  = (u8*)   alloc(131072);
    u8*    mbuf  = (u8*)   alloc((size_t)E*HD);

    int ntiles_n64 = N/64, ntiles_e = (E + 63)/64, ntiles_g = N/32;

    k_prep   <<<(176128+255)/256, 256, 0, stream>>>(W1, W2, W_enter, W_ih, W_hh, W1b, W2b, Wentb, Bgf8);
    hipMemsetAsync(deg, 0, (size_t)N*4, stream);
    hipMemsetAsync(cnt, 0, (size_t)N*4, stream);
    k_enter_mfma<<<ntiles_n64, 256, 0, stream>>>(x, Wentb, b_enter, att_r, xeb, Agru, r_dst, N);
    k_hist   <<<(E+255)/256, 256, 0, stream>>>(dst, deg, E);
    k_scan_a <<<N/1024, 256, 0, stream>>>(deg, rs, btot, N);
    k_scan_b <<<1, 256, 0, stream>>>(btot, bbase);
    k_scan_c <<<(N+255)/256, 256, 0, stream>>>(rs, bbase, N, E);
    k_scatter<<<(E+255)/256, 256, 0, stream>>>(dst, rs, cnt, epos, E);
    k_edge_mfma<<<1024, 512, 0, stream>>>(xeb, ea, W1b, att_l, r_dst, src, dst, epos,
                                          mbuf, alpha, ntiles_e, E);
    k_aggconv<<<ntiles_n64, 512, 0, stream>>>(rs, alpha, mbuf, W2b, b_conv, Agru, N);
    k_gru_mfma  <<<2048, 512, 0, stream>>>(Agru, xeb, Bgf8, b_ih, b_hh, out, N, ntiles_g);
}

// Round 14
// 509.827 us; speedup vs baseline: 1.0357x; 1.0290x over previous
//
#include <hip/hip_runtime.h>
#include <stdint.h>

#define HD  128
#define DIN 64
#define DE  32

typedef unsigned int u32; typedef unsigned short u16; typedef unsigned char u8;
typedef long i64_;
typedef short s16x8 __attribute__((ext_vector_type(8)));
typedef float f32x4 __attribute__((ext_vector_type(4)));
typedef float f32x2 __attribute__((ext_vector_type(2)));

#define MFMA16(a,b,c)  __builtin_amdgcn_mfma_f32_16x16x32_bf16((a),(b),(c),0,0,0)
#define MFMAF8(a,b,c)  __builtin_amdgcn_mfma_f32_16x16x32_fp8_fp8((a),(b),(c),0,0,0)

__device__ __forceinline__ float lrelu(float x){ return x > 0.f ? x : 0.01f*x; }
__device__ __forceinline__ float sigmoidf_(float x){ return 1.f/(1.f + __expf(-x)); }
__device__ __forceinline__ float tanhf_(float x){
    float t = fminf(fmaxf(x, -15.f), 15.f);
    float e = __expf(2.f*t);
    return (e - 1.f)/(e + 1.f);
}
__device__ __forceinline__ float eluf_(float x){ return x > 0.f ? x : expm1f(x); }

__device__ __forceinline__ u16 f32_to_bf16(float x){
    u32 u = __float_as_uint(x);
    u += 0x7FFFu + ((u >> 16) & 1u);
    return (u16)(u >> 16);
}
__device__ __forceinline__ float bf16lo(u32 u){ return __uint_as_float((u & 0xFFFFu) << 16); }
__device__ __forceinline__ float bf16hi(u32 u){ return __uint_as_float(u & 0xFFFF0000u); }
__device__ __forceinline__ float bf16f(u16 h){ return __uint_as_float(((u32)h) << 16); }
__device__ __forceinline__ u32 pk2(float a, float b){
    return (u32)f32_to_bf16(a) | ((u32)f32_to_bf16(b) << 16);
}
// HW OCP e4m3fn converters (gfx950)
__device__ __forceinline__ u8 hw_f8(float v){
    return (u8)__builtin_amdgcn_cvt_pk_fp8_f32(v, v, 0, false);
}
__device__ __forceinline__ u32 hw_f8x4(float a, float b, float c, float d){
    u32 r = (u32)__builtin_amdgcn_cvt_pk_fp8_f32(a, b, 0, false);
    r = (u32)__builtin_amdgcn_cvt_pk_fp8_f32(c, d, (int)r, true);
    return r;
}
__device__ __forceinline__ f32x2 hw_f8_dec2(u32 u){   // decodes bytes [0:1]
    return __builtin_amdgcn_cvt_pk_f32_fp8((int)u, false);
}
__device__ __forceinline__ f32x2 hw_f8_dec2_hi(u32 u){ // decodes bytes [2:3]
    return __builtin_amdgcn_cvt_pk_f32_fp8((int)u, true);
}

__device__ __forceinline__ float wave_max(float v){
    #pragma unroll
    for (int o = 32; o > 0; o >>= 1) v = fmaxf(v, __shfl_xor(v, o, 64));
    return v;
}
__device__ __forceinline__ float wave_sum(float v){
    #pragma unroll
    for (int o = 32; o > 0; o >>= 1) v += __shfl_xor(v, o, 64);
    return v;
}

// ---------------- weight prep: fp32 -> bf16 (+ fp8 GRU B-pack) ----------------
__global__ void k_prep(const float* __restrict__ W1, const float* __restrict__ W2,
                       const float* __restrict__ Went,
                       const float* __restrict__ Wih, const float* __restrict__ Whh,
                       u16* __restrict__ W1b, u16* __restrict__ W2b,
                       u16* __restrict__ Wentb, u8* __restrict__ Bgf8)
{
    int i = blockIdx.x*256 + threadIdx.x;
    if (i < 20480){ W1b[i] = f32_to_bf16(W1[i]); return; }
    i -= 20480;
    if (i < 16384){ W2b[i] = f32_to_bf16(W2[i]); return; }
    i -= 16384;
    if (i < 8192){ Wentb[i] = f32_to_bf16(Went[i]); return; }
    i -= 8192;
    if (i < 131072){
        int col = i >> 8, k = i & 255;
        int g = col >> 7, j = col & 127;
        float v;
        if      (g == 0) v = (k < 128) ? Wih[j*128 + k]        : Whh[j*128 + k - 128];
        else if (g == 1) v = (k < 128) ? Wih[(128+j)*128 + k]  : Whh[(128+j)*128 + k - 128];
        else if (g == 2) v = (k < 128) ? Wih[(256+j)*128 + k]  : 0.f;
        else             v = (k < 128) ? 0.f                   : Whh[(256+j)*128 + k - 128];
        Bgf8[i] = hw_f8(v);
    }
}

// ---------------- K1 (MFMA): xeb = bf16(lrelu(x@W^T+b)); Agru xe-half fp8; r_dst ----------------
__global__ __launch_bounds__(256, 4) void k_enter_mfma(
    const float* __restrict__ x, const u16* __restrict__ Wb, const float* __restrict__ be,
    const float* __restrict__ att_r, u16* __restrict__ xeb, u8* __restrict__ Agru,
    float* __restrict__ r_out, int N)
{
    __shared__ __align__(16) u8 sA[64*144];
    __shared__ __align__(16) u8 sO[64*272];
    int t = threadIdx.x, w = t >> 6, lane = t & 63, l15 = lane & 15, l4 = lane >> 4;
    int tile = blockIdx.x;

    s16x8 bfr[2][2];
    #pragma unroll
    for (int kf = 0; kf < 2; ++kf)
        #pragma unroll
        for (int cf = 0; cf < 2; ++cf)
            bfr[kf][cf] = *(const s16x8*)(Wb + (size_t)(w*32 + cf*16 + l15)*64 + kf*32 + l4*8);

    int el = t >> 2, q = t & 3;
    size_t n = (size_t)tile*64 + el;
    {
        const float4* xs = (const float4*)(x + n*64 + q*16);
        float4 f0 = xs[0], f1 = xs[1], f2 = xs[2], f3 = xs[3];
        uint4 o0, o1;
        o0.x = pk2(f0.x,f0.y); o0.y = pk2(f0.z,f0.w); o0.z = pk2(f1.x,f1.y); o0.w = pk2(f1.z,f1.w);
        o1.x = pk2(f2.x,f2.y); o1.y = pk2(f2.z,f2.w); o1.z = pk2(f3.x,f3.y); o1.w = pk2(f3.z,f3.w);
        *(uint4*)(sA + el*144 + q*32)      = o0;
        *(uint4*)(sA + el*144 + q*32 + 16) = o1;
    }
    __syncthreads();

    f32x4 acc[4][2];
    #pragma unroll
    for (int rf = 0; rf < 4; ++rf){ acc[rf][0] = (f32x4)0.f; acc[rf][1] = (f32x4)0.f; }
    #pragma unroll
    for (int kf = 0; kf < 2; ++kf){
        s16x8 a[4];
        #pragma unroll
        for (int rf = 0; rf < 4; ++rf)
            a[rf] = *(const s16x8*)(sA + (rf*16 + l15)*144 + kf*64 + l4*16);
        #pragma unroll
        for (int rf = 0; rf < 4; ++rf){
            acc[rf][0] = MFMA16(a[rf], bfr[kf][0], acc[rf][0]);
            acc[rf][1] = MFMA16(a[rf], bfr[kf][1], acc[rf][1]);
        }
    }
    float b0 = be[w*32 + l15], b1 = be[w*32 + 16 + l15];
    #pragma unroll
    for (int rf = 0; rf < 4; ++rf)
        #pragma unroll
        for (int r = 0; r < 4; ++r){
            int row = rf*16 + l4*4 + r;
            *(u16*)(sO + row*272 + (w*32 + l15)*2)      = f32_to_bf16(lrelu(acc[rf][0][r] + b0));
            *(u16*)(sO + row*272 + (w*32 + 16 + l15)*2) = f32_to_bf16(lrelu(acc[rf][1][r] + b1));
        }
    __syncthreads();

    float dot = 0.f;
    #pragma unroll
    for (int i = 0; i < 4; ++i){
        uint4 v = *(const uint4*)(sO + el*272 + q*64 + 16*i);
        ((uint4*)xeb)[n*16 + q*4 + i] = v;
        float f0 = bf16lo(v.x), f1 = bf16hi(v.x), f2 = bf16lo(v.y), f3 = bf16hi(v.y);
        float f4 = bf16lo(v.z), f5 = bf16hi(v.z), f6 = bf16lo(v.w), f7 = bf16hi(v.w);
        const float* al = att_r + q*32 + 8*i;
        dot = fmaf(f0, al[0], dot); dot = fmaf(f1, al[1], dot);
        dot = fmaf(f2, al[2], dot); dot = fmaf(f3, al[3], dot);
        dot = fmaf(f4, al[4], dot); dot = fmaf(f5, al[5], dot);
        dot = fmaf(f6, al[6], dot); dot = fmaf(f7, al[7], dot);
        uint2 p; p.x = hw_f8x4(f0, f1, f2, f3); p.y = hw_f8x4(f4, f5, f6, f7);
        *(uint2*)(Agru + n*256 + 128 + q*32 + i*8) = p;   // xe half (K>=128)
    }
    dot += __shfl_xor(dot, 1); dot += __shfl_xor(dot, 2);
    if (q == 0) r_out[n] = dot;
}

// ---------------- CSR build ----------------
__global__ void k_hist(const int* __restrict__ dst, int* __restrict__ deg, int E){
    int e = blockIdx.x*256 + threadIdx.x;
    if (e < E) atomicAdd(&deg[dst[e]], 1);
}
__global__ __launch_bounds__(256) void k_scan_a(
    const int* __restrict__ deg, int* __restrict__ rs, int* __restrict__ btot, int N)
{
    __shared__ int sd[256];
    int b = blockIdx.x, t = threadIdx.x;
    int base = b*1024 + t*4;
    int d0 = deg[base], d1 = deg[base+1], d2 = deg[base+2], d3 = deg[base+3];
    int s = d0 + d1 + d2 + d3;
    sd[t] = s; __syncthreads();
    for (int o = 1; o < 256; o <<= 1){
        int v = (t >= o) ? sd[t-o] : 0;
        __syncthreads();
        sd[t] += v;
        __syncthreads();
    }
    int ex = sd[t] - s;
    rs[base]   = ex;
    rs[base+1] = ex + d0;
    rs[base+2] = ex + d0 + d1;
    rs[base+3] = ex + d0 + d1 + d2;
    if (t == 0) btot[b] = sd[255];
}
__global__ __launch_bounds__(256) void k_scan_b(const int* __restrict__ btot, int* __restrict__ bbase){
    __shared__ int sd[256];
    int t = threadIdx.x;
    int s = btot[t];
    sd[t] = s; __syncthreads();
    for (int o = 1; o < 256; o <<= 1){
        int v = (t >= o) ? sd[t-o] : 0;
        __syncthreads();
        sd[t] += v;
        __syncthreads();
    }
    bbase[t] = sd[t] - s;
}
__global__ void k_scan_c(int* __restrict__ rs, const int* __restrict__ bbase, int N, int E){
    int i = blockIdx.x*256 + threadIdx.x;
    if (i < N) rs[i] += bbase[i >> 10];
    if (i == 0) rs[N] = E;
}
__global__ void k_scatter(const int* __restrict__ dst, const int* __restrict__ rs,
                          int* __restrict__ cnt, int* __restrict__ epos, int E){
    int e = blockIdx.x*256 + threadIdx.x;
    if (e >= E) return;
    int d = dst[e];
    int pos = rs[d] + atomicAdd(&cnt[d], 1);
    epos[e] = pos;
}

// ---------------- K2 (MFMA, 8-wave, 2-barrier pipeline, HW fp8): stores RAW dot ----------------
__global__ __launch_bounds__(512, 4) void k_edge_mfma(
    const u16* __restrict__ xeb, const float* __restrict__ ea,
    const u16* __restrict__ W1b, const float* __restrict__ att_l,
    const int* __restrict__ src, const int* __restrict__ epos,
    u8* __restrict__ m, float* __restrict__ alpha, int ntiles, int E)
{
    __shared__ __align__(16) u8 sA[64*336];
    __shared__ __align__(16) u8 sM[64*144];
    int t = threadIdx.x, w = t >> 6, lane = t & 63, l15 = lane & 15, l4 = lane >> 4;

    s16x8 bfr[5];                 // wave w owns cols [w*16, w*16+16)
    #pragma unroll
    for (int kf = 0; kf < 5; ++kf)
        bfr[kf] = *(const s16x8*)(W1b + (size_t)(w*16 + l15)*160 + kf*32 + l4*8);

    int el = t >> 3, q = t & 7;   // 64 edges/tile, 8 threads/edge
    int stride = gridDim.x;
    int tile = blockIdx.x;

    uint4 cx0, cx1;
    u32 ce0, ce1;
    int pe = 0;
    {
        int e = tile*64 + el;
        if (tile < ntiles && e < E){
            int sn = src[e];
            const uint4* xs = (const uint4*)xeb + (size_t)sn*16 + q*2;
            cx0 = xs[0]; cx1 = xs[1];
            float4 f = *(const float4*)(ea + (size_t)e*32 + q*4);
            ce0 = pk2(f.x, f.y); ce1 = pk2(f.z, f.w);
            pe  = epos[e];
        }
    }

    int ptile = -1;
    int pe_prev = 0;

    for (; tile < ntiles; tile += stride){
        int e = tile*64 + el;
        if (e < E){
            uint4* d = (uint4*)(sA + el*336 + q*32);
            d[0] = cx0; d[1] = cx1;
            *(u32*)(sA + el*336 + 256 + q*8)     = ce0;
            *(u32*)(sA + el*336 + 256 + q*8 + 4) = ce1;
        }
        int pe_cur = pe;

        int nt = tile + stride;
        if (nt < ntiles){
            int e2 = nt*64 + el;
            if (e2 < E){
                int sn = src[e2];
                const uint4* xs = (const uint4*)xeb + (size_t)sn*16 + q*2;
                cx0 = xs[0]; cx1 = xs[1];
                float4 f = *(const float4*)(ea + (size_t)e2*32 + q*4);
                ce0 = pk2(f.x, f.y); ce1 = pk2(f.z, f.w);
                pe  = epos[e2];
            }
        }

        // epilogue for previous tile (reads sM written last iteration)
        if (ptile >= 0){
            int ep = ptile*64 + el;
            if (ep < E){
                uint4 v = *(const uint4*)(sM + el*144 + q*16);
                ((uint4*)m)[(size_t)pe_prev*8 + q] = v;
                u32 ws[4] = {v.x, v.y, v.z, v.w};
                float dotv = 0.f;
                #pragma unroll
                for (int i = 0; i < 4; ++i){
                    f32x2 fa = hw_f8_dec2(ws[i]);
                    f32x2 fb = hw_f8_dec2_hi(ws[i]);
                    const float* al = att_l + q*16 + i*4;
                    dotv = fmaf(fa.x, al[0], dotv); dotv = fmaf(fa.y, al[1], dotv);
                    dotv = fmaf(fb.x, al[2], dotv); dotv = fmaf(fb.y, al[3], dotv);
                }
                dotv += __shfl_xor(dotv, 1); dotv += __shfl_xor(dotv, 2); dotv += __shfl_xor(dotv, 4);
                if (q == 0) alpha[pe_prev] = dotv;      // raw dot; lrelu(dot + r_dst) in k_aggconv
            }
        }
        __syncthreads();

        f32x4 acc[4];
        #pragma unroll
        for (int rf = 0; rf < 4; ++rf) acc[rf] = (f32x4)0.f;
        #pragma unroll
        for (int kf = 0; kf < 5; ++kf){
            s16x8 a[4];
            #pragma unroll
            for (int rf = 0; rf < 4; ++rf)
                a[rf] = *(const s16x8*)(sA + (rf*16 + l15)*336 + kf*64 + l4*16);
            #pragma unroll
            for (int rf = 0; rf < 4; ++rf)
                acc[rf] = MFMA16(a[rf], bfr[kf], acc[rf]);
        }

        int col = w*16 + l15;
        #pragma unroll
        for (int rf = 0; rf < 4; ++rf)
            #pragma unroll
            for (int r = 0; r < 4; ++r){
                int row = rf*16 + l4*4 + r;
                sM[row*144 + col] = hw_f8(lrelu(acc[rf][r]));
            }
        __syncthreads();

        ptile = tile; pe_prev = pe_cur;
    }

    if (ptile >= 0){
        int ep = ptile*64 + el;
        if (ep < E){
            uint4 v = *(const uint4*)(sM + el*144 + q*16);
            ((uint4*)m)[(size_t)pe_prev*8 + q] = v;
            u32 ws[4] = {v.x, v.y, v.z, v.w};
            float dotv = 0.f;
            #pragma unroll
            for (int i = 0; i < 4; ++i){
                f32x2 fa = hw_f8_dec2(ws[i]);
                f32x2 fb = hw_f8_dec2_hi(ws[i]);
                const float* al = att_l + q*16 + i*4;
                dotv = fmaf(fa.x, al[0], dotv); dotv = fmaf(fa.y, al[1], dotv);
                dotv = fmaf(fb.x, al[2], dotv); dotv = fmaf(fb.y, al[3], dotv);
            }
            dotv += __shfl_xor(dotv, 1); dotv += __shfl_xor(dotv, 2); dotv += __shfl_xor(dotv, 4);
            if (q == 0) alpha[pe_prev] = dotv;
        }
    }
}

// ---------------- K4+K5a fused: softmax-aggregate (raw dot + r_dst) -> W2 MFMA -> fp8 Agru ----------------
__global__ __launch_bounds__(512, 4) void k_aggconv(
    const int* __restrict__ rs, const float* __restrict__ alpha, const u8* __restrict__ m,
    const float* __restrict__ r_dst,
    const u16* __restrict__ W2b, const float* __restrict__ bc,
    u8* __restrict__ Agru, int N)
{
    __shared__ __align__(16) u8 sA[64*272];   // bf16 aggregated rows (+16B pad)
    __shared__ __align__(16) u8 sO[64*272];   // bf16 conv output rows
    int t = threadIdx.x, w = t >> 6, lane = t & 63, l15 = lane & 15, l4 = lane >> 4;
    int tile = blockIdx.x;

    s16x8 bfr[4];                 // wave w owns cols [w*16, w*16+16)
    #pragma unroll
    for (int kf = 0; kf < 4; ++kf)
        bfr[kf] = *(const s16x8*)(W2b + (size_t)(w*16 + l15)*128 + kf*32 + l4*8);

    // ---- phase 1: each wave aggregates 8 nodes into sA ----
    #pragma unroll 1
    for (int i = 0; i < 8; ++i){
        int nloc = w*8 + i;
        int n = tile*64 + nloc;
        int s = rs[n], tend = rs[n+1];
        int deg = tend - s;
        float rn = r_dst[n];
        float ax = 0.f, ay = 0.f;
        if (deg > 0 && deg <= 64){
            float av = -1e38f;
            if (lane < deg) av = lrelu(alpha[s + lane] + rn);
            float mx = wave_max(av);
            float ev = (lane < deg) ? __expf(av - mx) : 0.f;
            float ssum = wave_sum(ev);
            float wreg = ev / ssum;
            int k = 0;
            for (; k + 2 <= deg; k += 2){
                float w0 = __shfl(wreg, k);
                float w1 = __shfl(wreg, k + 1);
                u32 u0 = *(const u16*)(m + (size_t)(s + k)*HD + 2*lane);
                u32 u1 = *(const u16*)(m + (size_t)(s + k + 1)*HD + 2*lane);
                f32x2 f0 = hw_f8_dec2(u0);
                f32x2 f1 = hw_f8_dec2(u1);
                ax = fmaf(w0, f0.x, ax); ay = fmaf(w0, f0.y, ay);
                ax = fmaf(w1, f1.x, ax); ay = fmaf(w1, f1.y, ay);
            }
            if (k < deg){
                float w0 = __shfl(wreg, k);
                u32 u0 = *(const u16*)(m + (size_t)(s + k)*HD + 2*lane);
                f32x2 f0 = hw_f8_dec2(u0);
                ax = fmaf(w0, f0.x, ax); ay = fmaf(w0, f0.y, ay);
            }
        } else if (deg > 64){
            float mx = -1e38f;
            for (int k = lane; k < deg; k += 64) mx = fmaxf(mx, lrelu(alpha[s + k] + rn));
            mx = wave_max(mx);
            float ssum = 0.f;
            for (int k = lane; k < deg; k += 64) ssum += __expf(lrelu(alpha[s + k] + rn) - mx);
            ssum = wave_sum(ssum);
            float inv = 1.f / ssum;
            for (int k = 0; k < deg; ++k){
                float wgt = __expf(lrelu(alpha[s + k] + rn) - mx) * inv;
                u32 u0 = *(const u16*)(m + (size_t)(s + k)*HD + 2*lane);
                f32x2 f0 = hw_f8_dec2(u0);
                ax = fmaf(wgt, f0.x, ax);
                ay = fmaf(wgt, f0.y, ay);
            }
        }
        *(u32*)(sA + nloc*272 + lane*4) = pk2(ax, ay);
    }
    __syncthreads();

    // ---- phase 2: W2 @ sA + bias, elu, -> sO ----
    f32x4 acc[4];
    #pragma unroll
    for (int rf = 0; rf < 4; ++rf) acc[rf] = (f32x4)0.f;
    #pragma unroll
    for (int kf = 0; kf < 4; ++kf){
        s16x8 av[4];
        #pragma unroll
        for (int rf = 0; rf < 4; ++rf)
            av[rf] = *(const s16x8*)(sA + (rf*16 + l15)*272 + kf*64 + l4*16);
        #pragma unroll
        for (int rf = 0; rf < 4; ++rf)
            acc[rf] = MFMA16(av[rf], bfr[kf], acc[rf]);
    }
    float b0 = bc[w*16 + l15];
    #pragma unroll
    for (int rf = 0; rf < 4; ++rf)
        #pragma unroll
        for (int r = 0; r < 4; ++r){
            int row = rf*16 + l4*4 + r;
            *(u16*)(sO + row*272 + (w*16 + l15)*2) = f32_to_bf16(eluf_(acc[rf][r] + b0));
        }
    __syncthreads();

    // ---- write Agru h-half fp8 (8 threads/row, 16 cols each) ----
    {
        int el = t >> 3, q = t & 7;
        size_t n = (size_t)tile*64 + el;
        uint4 v0 = *(const uint4*)(sO + el*272 + q*32);
        uint4 v1 = *(const uint4*)(sO + el*272 + q*32 + 16);
        uint4 p;
        p.x = hw_f8x4(bf16lo(v0.x), bf16hi(v0.x), bf16lo(v0.y), bf16hi(v0.y));
        p.y = hw_f8x4(bf16lo(v0.z), bf16hi(v0.z), bf16lo(v0.w), bf16hi(v0.w));
        p.z = hw_f8x4(bf16lo(v1.x), bf16hi(v1.x), bf16lo(v1.y), bf16hi(v1.y));
        p.w = hw_f8x4(bf16lo(v1.z), bf16hi(v1.z), bf16lo(v1.w), bf16hi(v1.w));
        *(uint4*)(Agru + n*256 + q*16) = p;            // h half (K<128)
    }
}

// ---------------- K5b (fp8 MFMA): GRU cell + fused LayerNorm -> out ----------------
__global__ __launch_bounds__(512, 4) void k_gru_mfma(
    const u8* __restrict__ Agru, const u16* __restrict__ xeb, const u8* __restrict__ Bgf8,
    const float* __restrict__ bih, const float* __restrict__ bhh,
    float* __restrict__ out, int N, int ntiles)
{
    __shared__ __align__(16) u8 sA[32*272];
    __shared__ __align__(16) u8 sX[32*272];
    __shared__ __align__(16) float sOut[32*132];
    int t = threadIdx.x, w = t >> 6, lane = t & 63, l15 = lane & 15, l4 = lane >> 4;

    i64_ bfr0[8], bfr1[8], bfr2[4], bfr3[4];
    {
        int jc = w*16 + l15;
        #pragma unroll
        for (int kf = 0; kf < 8; ++kf){
            bfr0[kf] = *(const i64_*)(Bgf8 + (size_t)(jc)*256       + kf*32 + l4*8);
            bfr1[kf] = *(const i64_*)(Bgf8 + (size_t)(128 + jc)*256 + kf*32 + l4*8);
        }
        #pragma unroll
        for (int kf = 0; kf < 4; ++kf){
            bfr2[kf] = *(const i64_*)(Bgf8 + (size_t)(256 + jc)*256 + kf*32 + l4*8);
            bfr3[kf] = *(const i64_*)(Bgf8 + (size_t)(384 + jc)*256 + (kf+4)*32 + l4*8);
        }
    }
    int j = w*16 + l15;
    float rb = bih[j] + bhh[j];
    float zb = bih[128 + j] + bhh[128 + j];
    float ib = bih[256 + j];
    float hb = bhh[256 + j];

    int el = t >> 4, part = t & 15;
    int stride = gridDim.x;
    int tile = blockIdx.x;
    uint4 pa, px;
    if (tile < ntiles){
        pa = *((const uint4*)Agru + ((size_t)tile*32 + el)*16 + part);
        px = *((const uint4*)xeb  + ((size_t)tile*32 + el)*16 + part);
    }

    for (; tile < ntiles; tile += stride){
        *(uint4*)(sA + el*272 + part*16) = pa;
        *(uint4*)(sX + el*272 + part*16) = px;
        __syncthreads();

        int nt = tile + stride;
        if (nt < ntiles){
            pa = *((const uint4*)Agru + ((size_t)nt*32 + el)*16 + part);
            px = *((const uint4*)xeb  + ((size_t)nt*32 + el)*16 + part);
        }

        f32x4 acc[2][4];
        #pragma unroll
        for (int rf = 0; rf < 2; ++rf)
            #pragma unroll
            for (int g = 0; g < 4; ++g) acc[rf][g] = (f32x4)0.f;
        #pragma unroll
        for (int kf = 0; kf < 8; ++kf){
            i64_ a0 = *(const i64_*)(sA + l15*272 + kf*32 + l4*8);
            i64_ a1 = *(const i64_*)(sA + (16 + l15)*272 + kf*32 + l4*8);
            acc[0][0] = MFMAF8(a0, bfr0[kf], acc[0][0]);
            acc[1][0] = MFMAF8(a1, bfr0[kf], acc[1][0]);
            acc[0][1] = MFMAF8(a0, bfr1[kf], acc[0][1]);
            acc[1][1] = MFMAF8(a1, bfr1[kf], acc[1][1]);
            if (kf < 4){
                acc[0][2] = MFMAF8(a0, bfr2[kf], acc[0][2]);
                acc[1][2] = MFMAF8(a1, bfr2[kf], acc[1][2]);
            } else {
                acc[0][3] = MFMAF8(a0, bfr3[kf-4], acc[0][3]);
                acc[1][3] = MFMAF8(a1, bfr3[kf-4], acc[1][3]);
            }
        }
        #pragma unroll
        for (int rf = 0; rf < 2; ++rf)
            #pragma unroll
            for (int r = 0; r < 4; ++r){
                int rl = rf*16 + l4*4 + r;
                float rr = sigmoidf_(acc[rf][0][r] + rb);
                float zz = sigmoidf_(acc[rf][1][r] + zb);
                float iv = acc[rf][2][r] + ib;
                float hv = acc[rf][3][r] + hb;
                float nc = tanhf_(iv + rr*hv);
                float xej = bf16f(*(const u16*)(sX + rl*272 + 2*j));
                float v = (1.f - zz)*nc + zz*xej;
                v = fmaxf(v, 0.f);
                sOut[rl*132 + j] = v;
            }
        __syncthreads();
        {
            int row = t >> 4, sub = t & 15;
            const float* rp = sOut + row*132 + sub*8;
            float v0 = rp[0], v1 = rp[1], v2 = rp[2], v3 = rp[3];
            float v4 = rp[4], v5 = rp[5], v6 = rp[6], v7 = rp[7];
            float s1 = v0+v1+v2+v3+v4+v5+v6+v7;
            float s2 = v0*v0+v1*v1+v2*v2+v3*v3+v4*v4+v5*v5+v6*v6+v7*v7;
            #pragma unroll
            for (int o = 1; o < 16; o <<= 1){ s1 += __shfl_xor(s1, o); s2 += __shfl_xor(s2, o); }
            float mu  = s1 * (1.f/128.f);
            float var = s2 * (1.f/128.f) - mu*mu;
            var = fmaxf(var, 0.f);
            float rsd = rsqrtf(var + 1e-5f);
            float* op = out + ((size_t)tile*32 + row)*128 + sub*8;
            float4 o0, o1;
            o0.x = (v0-mu)*rsd; o0.y = (v1-mu)*rsd; o0.z = (v2-mu)*rsd; o0.w = (v3-mu)*rsd;
            o1.x = (v4-mu)*rsd; o1.y = (v5-mu)*rsd; o1.z = (v6-mu)*rsd; o1.w = (v7-mu)*rsd;
            ((float4*)op)[0] = o0; ((float4*)op)[1] = o1;
        }
        __syncthreads();
    }
}

// ---------------- host ----------------
extern "C" void kernel_launch(void* const* d_in, const int* in_sizes, int n_in,
                              void* d_out, int out_size, void* d_ws, size_t ws_size,
                              hipStream_t stream)
{
    const float* x       = (const float*)d_in[0];
    const float* ea      = (const float*)d_in[1];
    const float* W_enter = (const float*)d_in[2];
    const float* b_enter = (const float*)d_in[3];
    const float* W1      = (const float*)d_in[4];
    const float* att_l   = (const float*)d_in[5];
    const float* att_r   = (const float*)d_in[6];
    const float* W2      = (const float*)d_in[7];
    const float* b_conv  = (const float*)d_in[8];
    const float* W_ih    = (const float*)d_in[9];
    const float* W_hh    = (const float*)d_in[10];
    const float* b_ih    = (const float*)d_in[11];
    const float* b_hh    = (const float*)d_in[12];
    const int*   eidx    = (const int*)d_in[13];

    int N = in_sizes[0] / DIN;
    int E = in_sizes[13] / 2;
    const int* src = eidx;
    const int* dst = eidx + E;
    float* out = (float*)d_out;

    size_t off = 0;
    char* base = (char*)d_ws;
    auto alloc = [&](size_t bytes) -> char* {
        char* p = base + off;
        off = (off + bytes + 255) & ~(size_t)255;
        return p;
    };
    u16*   xeb   = (u16*)  alloc((size_t)N*HD*2);
    u8*    Agru  = (u8*)   alloc((size_t)N*256);
    float* r_dst = (float*)alloc((size_t)N*4);
    float* alpha = (float*)alloc((size_t)E*4);
    int*   deg   = (int*)  alloc((size_t)N*4);
    int*   rs    = (int*)  alloc((size_t)(N+1)*4);
    int*   cnt   = (int*)  alloc((size_t)N*4);
    int*   epos  = (int*)  alloc((size_t)E*4);
    int*   btot  = (int*)  alloc(1024);
    int*   bbase = (int*)  alloc(1024);
    u16*   W1b   = (u16*)  alloc(20480*2);
    u16*   W2b   = (u16*)  alloc(16384*2);
    u16*   Wentb = (u16*)  alloc(8192*2);
    u8*    Bgf8  = (u8*)   alloc(131072);
    u8*    mbuf  = (u8*)   alloc((size_t)E*HD);

    int ntiles_n64 = N/64, ntiles_e = (E + 63)/64, ntiles_g = N/32;

    k_prep   <<<(176128+255)/256, 256, 0, stream>>>(W1, W2, W_enter, W_ih, W_hh, W1b, W2b, Wentb, Bgf8);
    hipMemsetAsync(deg, 0, (size_t)N*4, stream);
    hipMemsetAsync(cnt, 0, (size_t)N*4, stream);
    k_enter_mfma<<<ntiles_n64, 256, 0, stream>>>(x, Wentb, b_enter, att_r, xeb, Agru, r_dst, N);
    k_hist   <<<(E+255)/256, 256, 0, stream>>>(dst, deg, E);
    k_scan_a <<<N/1024, 256, 0, stream>>>(deg, rs, btot, N);
    k_scan_b <<<1, 256, 0, stream>>>(btot, bbase);
    k_scan_c <<<(N+255)/256, 256, 0, stream>>>(rs, bbase, N, E);
    k_scatter<<<(E+255)/256, 256, 0, stream>>>(dst, rs, cnt, epos, E);
    k_edge_mfma<<<1024, 512, 0, stream>>>(xeb, ea, W1b, att_l, src, epos,
                                          mbuf, alpha, ntiles_e, E);
    k_aggconv<<<ntiles_n64, 512, 0, stream>>>(rs, alpha, mbuf, r_dst, W2b, b_conv, Agru, N);
    k_gru_mfma  <<<1024, 512, 0, stream>>>(Agru, xeb, Bgf8, b_ih, b_hh, out, N, ntiles_g);
}